// Round 5
// baseline (135.670 us; speedup 1.0000x reference)
//
#include <hip/hip_runtime.h>

#define SENT    256
#define BATCH   64
#define WLEN    16
#define D_WORDE 300
#define D_CHARE 50
#define OUT_CH  200
#define KSIZE   3
#define NPOS    14
#define D_OUT   500
#define NWORDS  (SENT * BATCH)

// GEMM geometry: M=16 positions/word, N=13x16=208, K=3*64=192 (kg=kk*64+c)
#define KPAD      192
#define MPAD      208
#define CHARP_U16 (129 * 64)          // row 128 = zeros (conv rows 16/17)
#define WO_U16    (MPAD * KPAD)
#define WS_NEED   ((size_t)(CHARP_U16 + WO_U16) * 2)

#define WPB         8                 // words per block
#define TILE_U16    1160              // 18*64 + 8 pad (per-word LDS tile, ushorts)
#define CONV_BLOCKS (NWORDS / WPB)    // 2048 = 8 blocks/CU exactly

typedef short  short8  __attribute__((ext_vector_type(8)));
typedef ushort ushort8 __attribute__((ext_vector_type(8)));
typedef float  float4v __attribute__((ext_vector_type(4)));

__device__ __forceinline__ ushort f2bf(float f) {
    unsigned u = __float_as_uint(f);
    u = (u + 0x7FFFu + ((u >> 16) & 1u)) >> 16;   // RNE
    return (ushort)u;
}

// ---------- prep: bf16 char table (129 rows) + K-major conv weights ----------
__global__ void prep_kernel(const float* __restrict__ W_char,
                            const float* __restrict__ conv_w,
                            ushort* __restrict__ ws) {
    int j = blockIdx.x * 256 + threadIdx.x;
    if (j < CHARP_U16) {
        int r = j >> 6, c = j & 63;
        ws[j] = (r < 128 && c < D_CHARE) ? f2bf(W_char[r * D_CHARE + c]) : (ushort)0;
    }
    int j2 = j - CHARP_U16;
    if (j2 >= 0 && j2 < WO_U16) {
        int o = j2 / KPAD, kg = j2 - o * KPAD;
        int kk = kg >> 6, c = kg & 63;
        float v = (o < OUT_CH && c < D_CHARE)
                    ? conv_w[o * (D_CHARE * KSIZE) + c * KSIZE + kk] : 0.f;
        ws[CHARP_U16 + j2] = f2bf(v);
    }
}

__device__ __forceinline__ float redmax14(float4v d, int lg) {
    float m01 = fmaxf(d[0], d[1]);
    float m23 = fmaxf(d[2], d[3]);
    float m = (lg == 3) ? m01 : fmaxf(m01, m23);   // rows 14,15 invalid
    m = fmaxf(m, __shfl_xor(m, 16, 64));
    m = fmaxf(m, __shfl_xor(m, 32, 64));
    return m;
}

// ---------- fused uniform block: conv (MFMA) + word-emb copy tail ----------
__global__ void __launch_bounds__(256, 8)
fused_kernel(const int* __restrict__ words, const int* __restrict__ chars,
             const float* __restrict__ W_word, const ushort* __restrict__ ws,
             const float* __restrict__ conv_b, float* __restrict__ out) {
    __shared__ __align__(16) ushort smem[WPB * TILE_U16];
    __shared__ int ids[WPB * WLEN];

    const int tid  = threadIdx.x;
    const int lane = tid & 63;
    const int wave = tid >> 6;

    const ushort* __restrict__ charP = ws;
    const ushort* __restrict__ WO    = ws + CHARP_U16;
    const int block0 = blockIdx.x * WPB;
    const int l15 = lane & 15;
    const int lg  = lane >> 4;

    // ---- stage char ids
    if (tid < WPB * WLEN) {
        int w = tid >> 4, l = tid & 15;
        int m = block0 + w;
        ids[tid] = chars[((m & 63) * SENT + (m >> 6)) * WLEN + l];
    }
    __syncthreads();

    // ---- stage 8 word-tiles (18 rows x 64 bf16, XOR-swizzled 16B blocks)
    #pragma unroll
    for (int task = tid; task < WPB * 144; task += 256) {
        int word = task / 144;
        int rem  = task - word * 144;
        int l = rem >> 3, blk = rem & 7;
        ushort8 v = {};
        if (l < WLEN) {
            int id = ids[(word << 4) | l];
            v = *(const ushort8*)&charP[id * 64 + blk * 8];
        }
        *(ushort8*)&smem[word * TILE_U16 + l * 64 + ((blk ^ (l & 7)) << 3)] = v;
    }
    __syncthreads();

    // ---- phase 1: wave w owns N-tiles {w, w+4, w+8}; all 8 words
    {
        short8 B[3][6];
        float  bv[3];
        #pragma unroll
        for (int i = 0; i < 3; i++) {
            int col = (wave + 4 * i) * 16 + l15;              // <= 191, all valid
            #pragma unroll
            for (int s = 0; s < 6; s++)
                B[i][s] = *(const short8*)&WO[col * KPAD + s * 32 + lg * 8];
            bv[i] = conv_b[col];
        }

        #pragma unroll 1
        for (int r = 0; r < WPB; r++) {
            const int base = r * TILE_U16;
            short8 a[6];
            #pragma unroll
            for (int s = 0; s < 6; s++) {
                int l  = l15 + (s >> 1);
                int bb = (((s & 1) * 4 + lg) ^ (l & 7));
                a[s] = *(const short8*)&smem[base + l * 64 + (bb << 3)];
            }
            float4v acc[3];
            #pragma unroll
            for (int i = 0; i < 3; i++) acc[i] = (float4v){0, 0, 0, 0};
            #pragma unroll
            for (int s = 0; s < 6; s++)
                #pragma unroll
                for (int i = 0; i < 3; i++)
                    acc[i] = __builtin_amdgcn_mfma_f32_16x16x32_bf16(a[s], B[i][s], acc[i], 0, 0, 0);

            float* obase = out + (size_t)(block0 + r) * D_OUT + D_WORDE;
            #pragma unroll
            for (int i = 0; i < 3; i++) {
                float mx = redmax14(acc[i], lg) + bv[i];
                if (lane < 16) obase[(wave + 4 * i) * 16 + lane] = mx;
            }
        }
    }

    // ---- phase 2: tile 12 (channels 192..199); wave w does words {2w, 2w+1}
    {
        short8 B12[6];
        #pragma unroll
        for (int s = 0; s < 6; s++)
            B12[s] = *(const short8*)&WO[(192 + l15) * KPAD + s * 32 + lg * 8];
        const float bv12 = (192 + l15 < OUT_CH) ? conv_b[192 + l15] : 0.f;

        #pragma unroll 1
        for (int r2 = 0; r2 < 2; r2++) {
            const int widx = 2 * wave + r2;
            const int base = widx * TILE_U16;
            short8 a[6];
            #pragma unroll
            for (int s = 0; s < 6; s++) {
                int l  = l15 + (s >> 1);
                int bb = (((s & 1) * 4 + lg) ^ (l & 7));
                a[s] = *(const short8*)&smem[base + l * 64 + (bb << 3)];
            }
            float4v acc = {0, 0, 0, 0};
            #pragma unroll
            for (int s = 0; s < 6; s++)
                acc = __builtin_amdgcn_mfma_f32_16x16x32_bf16(a[s], B12[s], acc, 0, 0, 0);
            float mx = redmax14(acc, lg) + bv12;
            if (lane < 8)
                out[(size_t)(block0 + widx) * D_OUT + D_WORDE + 192 + lane] = mx;
        }
    }

    // ---- memory tail: word-emb copy for this block's 8 words (2 rows/wave)
    #pragma unroll
    for (int r = 0; r < 2; r++) {
        const int m   = block0 + wave * 2 + r;
        const int idx = words[m];
        const float4v* __restrict__ src = (const float4v*)(W_word + (size_t)idx * D_WORDE);
        float4v* __restrict__ dst = (float4v*)(out + (size_t)m * D_OUT);
        float4v v0 = src[lane];
        dst[lane] = v0;                                        // 75 float4 per row
        if (lane < 75 - 64) dst[64 + lane] = src[64 + lane];
    }
}

// ---------- fallbacks (tiny ws): round-1 proven kernels ----------
__global__ void __launch_bounds__(256)
word_emb_kernel(const int* __restrict__ words, const float* __restrict__ W_word,
                float* __restrict__ out) {
    int wave = threadIdx.x >> 6, lane = threadIdx.x & 63;
    int m = blockIdx.x * 4 + wave;
    int idx = words[m];
    const float* __restrict__ src = W_word + (size_t)idx * D_WORDE;
    float* __restrict__ dst = out + (size_t)m * D_OUT;
    for (int j = lane; j < D_WORDE; j += 64) dst[j] = src[j];
}

__global__ void __launch_bounds__(256)
char_conv_f32_kernel(const int* __restrict__ chars, const float* __restrict__ W_char,
                     const float* __restrict__ conv_w, const float* __restrict__ conv_b,
                     float* __restrict__ out) {
    __shared__ __align__(16) float xs[D_CHARE * WLEN];
    __shared__ int ids[WLEN];
    int m = blockIdx.x, s = m >> 6, b = m & 63, tid = threadIdx.x;
    if (tid < WLEN) ids[tid] = chars[(b * SENT + s) * WLEN + tid];
    __syncthreads();
    for (int e = tid; e < D_CHARE * WLEN; e += 256) {
        int c = e >> 4, l = e & 15;
        xs[e] = W_char[ids[l] * D_CHARE + c];
    }
    __syncthreads();
    if (tid < OUT_CH) {
        float acc[NPOS];
        #pragma unroll
        for (int p = 0; p < NPOS; p++) acc[p] = 0.f;
        const float4* xs4 = (const float4*)xs;
        for (int c = 0; c < D_CHARE; c++) {
            float4 a0 = xs4[c*4+0], a1 = xs4[c*4+1], a2 = xs4[c*4+2], a3 = xs4[c*4+3];
            float xr[WLEN] = {a0.x,a0.y,a0.z,a0.w, a1.x,a1.y,a1.z,a1.w,
                              a2.x,a2.y,a2.z,a2.w, a3.x,a3.y,a3.z,a3.w};
            #pragma unroll
            for (int k = 0; k < KSIZE; k++) {
                float wv = conv_w[tid * (D_CHARE * KSIZE) + c * KSIZE + k];
                #pragma unroll
                for (int p = 0; p < NPOS; p++) acc[p] = fmaf(wv, xr[p + k], acc[p]);
            }
        }
        float mx = acc[0];
        #pragma unroll
        for (int p = 1; p < NPOS; p++) mx = fmaxf(mx, acc[p]);
        out[(size_t)m * D_OUT + D_WORDE + tid] = mx + conv_b[tid];
    }
}

extern "C" void kernel_launch(void* const* d_in, const int* in_sizes, int n_in,
                              void* d_out, int out_size, void* d_ws, size_t ws_size,
                              hipStream_t stream) {
    const int*   words  = (const int*)d_in[0];
    const int*   chars  = (const int*)d_in[1];
    const float* W_word = (const float*)d_in[2];
    const float* W_char = (const float*)d_in[3];
    const float* conv_w = (const float*)d_in[4];
    const float* conv_b = (const float*)d_in[5];
    float* out = (float*)d_out;

    if (ws_size >= WS_NEED) {
        ushort* ws = (ushort*)d_ws;
        hipLaunchKernelGGL(prep_kernel,
                           dim3((CHARP_U16 + WO_U16 + 255) / 256), dim3(256), 0, stream,
                           W_char, conv_w, ws);
        hipLaunchKernelGGL(fused_kernel, dim3(CONV_BLOCKS), dim3(256), 0, stream,
                           words, chars, W_word, ws, conv_b, out);
    } else {
        hipLaunchKernelGGL(word_emb_kernel, dim3(NWORDS / 4), dim3(256), 0, stream,
                           words, W_word, out);
        hipLaunchKernelGGL(char_conv_f32_kernel, dim3(NWORDS), dim3(256), 0, stream,
                           chars, W_char, conv_w, conv_b, out);
    }
}

// Round 6
// 112.473 us; speedup vs baseline: 1.2062x; 1.2062x over previous
//
#include <hip/hip_runtime.h>

#define SENT    256
#define BATCH   64
#define WLEN    16
#define D_WORDE 300
#define D_CHARE 50
#define OUT_CH  200
#define KSIZE   3
#define NPOS    14
#define D_OUT   500
#define NWORDS  (SENT * BATCH)

// GEMM geometry: M=16 positions/word, N=13x16=208, K=3*64=192 (kg=kk*64+c)
#define KPAD      192
#define MPAD      208
#define CHARP_U16 (129 * 64)          // row 128 = zeros (conv rows 16/17)
#define WO_U16    (MPAD * KPAD)
#define WS_NEED   ((size_t)(CHARP_U16 + WO_U16) * 2)

#define WPB         8                 // words per block
#define TILE_U16    1160              // 18*64 + 8 pad (per-word LDS tile, ushorts)
#define CONV_BLOCKS (NWORDS / WPB)    // 2048

typedef short  short8  __attribute__((ext_vector_type(8)));
typedef ushort ushort8 __attribute__((ext_vector_type(8)));
typedef float  float4v __attribute__((ext_vector_type(4)));

__device__ __forceinline__ ushort f2bf(float f) {
    unsigned u = __float_as_uint(f);
    u = (u + 0x7FFFu + ((u >> 16) & 1u)) >> 16;   // RNE
    return (ushort)u;
}

// ---------- prep: bf16 char table (129 rows) + K-major conv weights ----------
__global__ void prep_kernel(const float* __restrict__ W_char,
                            const float* __restrict__ conv_w,
                            ushort* __restrict__ ws) {
    int j = blockIdx.x * 256 + threadIdx.x;
    if (j < CHARP_U16) {
        int r = j >> 6, c = j & 63;
        ws[j] = (r < 128 && c < D_CHARE) ? f2bf(W_char[r * D_CHARE + c]) : (ushort)0;
    }
    int j2 = j - CHARP_U16;
    if (j2 >= 0 && j2 < WO_U16) {
        int o = j2 / KPAD, kg = j2 - o * KPAD;
        int kk = kg >> 6, c = kg & 63;
        float v = (o < OUT_CH && c < D_CHARE)
                    ? conv_w[o * (D_CHARE * KSIZE) + c * KSIZE + kk] : 0.f;
        ws[CHARP_U16 + j2] = f2bf(v);
    }
}

__device__ __forceinline__ float redmax14(float4v d, int lg) {
    float m01 = fmaxf(d[0], d[1]);
    float m23 = fmaxf(d[2], d[3]);
    float m = (lg == 3) ? m01 : fmaxf(m01, m23);   // rows 14,15 invalid
    m = fmaxf(m, __shfl_xor(m, 16, 64));
    m = fmaxf(m, __shfl_xor(m, 32, 64));
    return m;
}

// ---------- fused uniform block: conv (MFMA) + emb copy (issue-early/write-late)
// __launch_bounds__(256,6): VGPR cap ~85 >= ~80 live set (NO spill — round 5's
// (256,8) capped at 64 and spilled: VGPR=32, FETCH 336MB). 24 waves/CU.
__global__ void __launch_bounds__(256, 6)
fused_kernel(const int* __restrict__ words, const int* __restrict__ chars,
             const float* __restrict__ W_word, const ushort* __restrict__ ws,
             const float* __restrict__ conv_b, float* __restrict__ out) {
    __shared__ __align__(16) ushort smem[WPB * TILE_U16];
    __shared__ int ids[WPB * WLEN];

    const int tid  = threadIdx.x;
    const int lane = tid & 63;
    const int wave = tid >> 6;

    const ushort* __restrict__ charP = ws;
    const ushort* __restrict__ WO    = ws + CHARP_U16;
    const int block0 = blockIdx.x * WPB;
    const int l15 = lane & 15;
    const int lg  = lane >> 4;

    // ---- stage char ids
    if (tid < WPB * WLEN) {
        int w = tid >> 4, l = tid & 15;
        int m = block0 + w;
        ids[tid] = chars[((m & 63) * SENT + (m >> 6)) * WLEN + l];
    }
    __syncthreads();

    // ---- stage 8 word-tiles (18 rows x 64 bf16, XOR-swizzled 16B blocks)
    #pragma unroll
    for (int task = tid; task < WPB * 144; task += 256) {
        int word = task / 144;
        int rem  = task - word * 144;
        int l = rem >> 3, blk = rem & 7;
        ushort8 v = {};
        if (l < WLEN) {
            int id = ids[(word << 4) | l];
            v = *(const ushort8*)&charP[id * 64 + blk * 8];
        }
        *(ushort8*)&smem[word * TILE_U16 + l * 64 + ((blk ^ (l & 7)) << 3)] = v;
    }
    __syncthreads();

    // ---- T14 issue-early: this wave's 2 word-emb rows -> registers.
    // HBM gather latency (~900cy) hides under the MFMA phases below.
    const int me0 = block0 + wave * 2;
    const int me1 = me0 + 1;
    const float4v* __restrict__ s0 =
        (const float4v*)(W_word + (size_t)words[me0] * D_WORDE);
    const float4v* __restrict__ s1 =
        (const float4v*)(W_word + (size_t)words[me1] * D_WORDE);
    float4v e0 = s0[lane], e1 = s1[lane];          // 75 float4 per row
    float4v e0b = {}, e1b = {};
    if (lane < 75 - 64) { e0b = s0[64 + lane]; e1b = s1[64 + lane]; }

    // ---- phase 1: wave w owns N-tiles {w, w+4, w+8}; all 8 words
    {
        short8 B[3][6];
        float  bv[3];
        #pragma unroll
        for (int i = 0; i < 3; i++) {
            int col = (wave + 4 * i) * 16 + l15;              // <= 191, all valid
            #pragma unroll
            for (int s = 0; s < 6; s++)
                B[i][s] = *(const short8*)&WO[col * KPAD + s * 32 + lg * 8];
            bv[i] = conv_b[col];
        }

        #pragma unroll 1
        for (int r = 0; r < WPB; r++) {
            const int base = r * TILE_U16;
            short8 a[6];
            #pragma unroll
            for (int s = 0; s < 6; s++) {
                int l  = l15 + (s >> 1);
                int bb = (((s & 1) * 4 + lg) ^ (l & 7));
                a[s] = *(const short8*)&smem[base + l * 64 + (bb << 3)];
            }
            float4v acc[3];
            #pragma unroll
            for (int i = 0; i < 3; i++) acc[i] = (float4v){0, 0, 0, 0};
            #pragma unroll
            for (int s = 0; s < 6; s++)
                #pragma unroll
                for (int i = 0; i < 3; i++)
                    acc[i] = __builtin_amdgcn_mfma_f32_16x16x32_bf16(a[s], B[i][s], acc[i], 0, 0, 0);

            float* obase = out + (size_t)(block0 + r) * D_OUT + D_WORDE;
            #pragma unroll
            for (int i = 0; i < 3; i++) {
                float mx = redmax14(acc[i], lg) + bv[i];
                if (lane < 16) obase[(wave + 4 * i) * 16 + lane] = mx;
            }
        }
    }

    // ---- phase 2: tile 12 (channels 192..199); wave w does words {2w, 2w+1}
    {
        short8 B12[6];
        #pragma unroll
        for (int s = 0; s < 6; s++)
            B12[s] = *(const short8*)&WO[(192 + l15) * KPAD + s * 32 + lg * 8];
        const float bv12 = (192 + l15 < OUT_CH) ? conv_b[192 + l15] : 0.f;

        #pragma unroll 1
        for (int r2 = 0; r2 < 2; r2++) {
            const int widx = 2 * wave + r2;
            const int base = widx * TILE_U16;
            short8 a[6];
            #pragma unroll
            for (int s = 0; s < 6; s++) {
                int l  = l15 + (s >> 1);
                int bb = (((s & 1) * 4 + lg) ^ (l & 7));
                a[s] = *(const short8*)&smem[base + l * 64 + (bb << 3)];
            }
            float4v acc = {0, 0, 0, 0};
            #pragma unroll
            for (int s = 0; s < 6; s++)
                acc = __builtin_amdgcn_mfma_f32_16x16x32_bf16(a[s], B12[s], acc, 0, 0, 0);
            float mx = redmax14(acc, lg) + bv12;
            if (lane < 8)
                out[(size_t)(block0 + widx) * D_OUT + D_WORDE + 192 + lane] = mx;
        }
    }

    // ---- write-late: emb rows from registers
    {
        float4v* __restrict__ d0 = (float4v*)(out + (size_t)me0 * D_OUT);
        float4v* __restrict__ d1 = (float4v*)(out + (size_t)me1 * D_OUT);
        d0[lane] = e0;
        d1[lane] = e1;
        if (lane < 75 - 64) { d0[64 + lane] = e0b; d1[64 + lane] = e1b; }
    }
}

// ---------- fallbacks (tiny ws): round-1 proven kernels ----------
__global__ void __launch_bounds__(256)
word_emb_kernel(const int* __restrict__ words, const float* __restrict__ W_word,
                float* __restrict__ out) {
    int wave = threadIdx.x >> 6, lane = threadIdx.x & 63;
    int m = blockIdx.x * 4 + wave;
    int idx = words[m];
    const float* __restrict__ src = W_word + (size_t)idx * D_WORDE;
    float* __restrict__ dst = out + (size_t)m * D_OUT;
    for (int j = lane; j < D_WORDE; j += 64) dst[j] = src[j];
}

__global__ void __launch_bounds__(256)
char_conv_f32_kernel(const int* __restrict__ chars, const float* __restrict__ W_char,
                     const float* __restrict__ conv_w, const float* __restrict__ conv_b,
                     float* __restrict__ out) {
    __shared__ __align__(16) float xs[D_CHARE * WLEN];
    __shared__ int ids[WLEN];
    int m = blockIdx.x, s = m >> 6, b = m & 63, tid = threadIdx.x;
    if (tid < WLEN) ids[tid] = chars[(b * SENT + s) * WLEN + tid];
    __syncthreads();
    for (int e = tid; e < D_CHARE * WLEN; e += 256) {
        int c = e >> 4, l = e & 15;
        xs[e] = W_char[ids[l] * D_CHARE + c];
    }
    __syncthreads();
    if (tid < OUT_CH) {
        float acc[NPOS];
        #pragma unroll
        for (int p = 0; p < NPOS; p++) acc[p] = 0.f;
        const float4* xs4 = (const float4*)xs;
        for (int c = 0; c < D_CHARE; c++) {
            float4 a0 = xs4[c*4+0], a1 = xs4[c*4+1], a2 = xs4[c*4+2], a3 = xs4[c*4+3];
            float xr[WLEN] = {a0.x,a0.y,a0.z,a0.w, a1.x,a1.y,a1.z,a1.w,
                              a2.x,a2.y,a2.z,a2.w, a3.x,a3.y,a3.z,a3.w};
            #pragma unroll
            for (int k = 0; k < KSIZE; k++) {
                float wv = conv_w[tid * (D_CHARE * KSIZE) + c * KSIZE + k];
                #pragma unroll
                for (int p = 0; p < NPOS; p++) acc[p] = fmaf(wv, xr[p + k], acc[p]);
            }
        }
        float mx = acc[0];
        #pragma unroll
        for (int p = 1; p < NPOS; p++) mx = fmaxf(mx, acc[p]);
        out[(size_t)m * D_OUT + D_WORDE + tid] = mx + conv_b[tid];
    }
}

extern "C" void kernel_launch(void* const* d_in, const int* in_sizes, int n_in,
                              void* d_out, int out_size, void* d_ws, size_t ws_size,
                              hipStream_t stream) {
    const int*   words  = (const int*)d_in[0];
    const int*   chars  = (const int*)d_in[1];
    const float* W_word = (const float*)d_in[2];
    const float* W_char = (const float*)d_in[3];
    const float* conv_w = (const float*)d_in[4];
    const float* conv_b = (const float*)d_in[5];
    float* out = (float*)d_out;

    if (ws_size >= WS_NEED) {
        ushort* ws = (ushort*)d_ws;
        hipLaunchKernelGGL(prep_kernel,
                           dim3((CHARP_U16 + WO_U16 + 255) / 256), dim3(256), 0, stream,
                           W_char, conv_w, ws);
        hipLaunchKernelGGL(fused_kernel, dim3(CONV_BLOCKS), dim3(256), 0, stream,
                           words, chars, W_word, ws, conv_b, out);
    } else {
        hipLaunchKernelGGL(word_emb_kernel, dim3(NWORDS / 4), dim3(256), 0, stream,
                           words, W_word, out);
        hipLaunchKernelGGL(char_conv_f32_kernel, dim3(NWORDS), dim3(256), 0, stream,
                           chars, W_char, conv_w, conv_b, out);
    }
}

// Round 7
// 91.661 us; speedup vs baseline: 1.4801x; 1.2270x over previous
//
#include <hip/hip_runtime.h>

#define SENT    256
#define BATCH   64
#define WLEN    16
#define D_WORDE 300
#define D_CHARE 50
#define OUT_CH  200
#define KSIZE   3
#define NPOS    14
#define D_OUT   500
#define NWORDS  (SENT * BATCH)

// GEMM geometry: M=16 positions/word, N=13x16=208, K=3*64=192 (kg=kk*64+c)
#define KPAD      192
#define MPAD      208
#define CHARP_U16 (129 * 64)          // row 128 = zeros (conv rows 16/17)
#define WO_U16    (MPAD * KPAD)
#define WS_NEED   ((size_t)(CHARP_U16 + WO_U16) * 2)

// barrier-free decomposition: 6 classes x 2 tiles x 8-word strips + tile12 x 32-word strips
#define NCLS        6
#define WPW         8
#define T12_WPW     32
#define CLASS_WAVES (NWORDS / WPW)                       // 2048
#define T12_WAVES   (NWORDS / T12_WPW)                   // 512
#define CONV_WAVES  (NCLS * CLASS_WAVES + T12_WAVES)     // 12800
#define CONV_BLOCKS (CONV_WAVES / 4)                     // 3200
#define GRID        8192                                 // even: conv (cb<3200), odd: emb (4096)

#define SLICE 1160                    // ushorts per wave buffer (18*64 + 8 pad)

typedef short  short8  __attribute__((ext_vector_type(8)));
typedef ushort ushort8 __attribute__((ext_vector_type(8)));
typedef float  float4v __attribute__((ext_vector_type(4)));

__device__ __forceinline__ ushort f2bf(float f) {
    unsigned u = __float_as_uint(f);
    u = (u + 0x7FFFu + ((u >> 16) & 1u)) >> 16;   // RNE
    return (ushort)u;
}

// ---------- prep: bf16 char table (129 rows) + K-major conv weights ----------
__global__ void prep_kernel(const float* __restrict__ W_char,
                            const float* __restrict__ conv_w,
                            ushort* __restrict__ ws) {
    int j = blockIdx.x * 256 + threadIdx.x;
    if (j < CHARP_U16) {
        int r = j >> 6, c = j & 63;
        ws[j] = (r < 128 && c < D_CHARE) ? f2bf(W_char[r * D_CHARE + c]) : (ushort)0;
    }
    int j2 = j - CHARP_U16;
    if (j2 >= 0 && j2 < WO_U16) {
        int o = j2 / KPAD, kg = j2 - o * KPAD;
        int kk = kg >> 6, c = kg & 63;
        float v = (o < OUT_CH && c < D_CHARE)
                    ? conv_w[o * (D_CHARE * KSIZE) + c * KSIZE + kk] : 0.f;
        ws[CHARP_U16 + j2] = f2bf(v);
    }
}

__device__ __forceinline__ float redmax14(float4v d, int lg) {
    float m01 = fmaxf(d[0], d[1]);
    float m23 = fmaxf(d[2], d[3]);
    float m = (lg == 3) ? m01 : fmaxf(m01, m23);   // rows 14,15 invalid
    m = fmaxf(m, __shfl_xor(m, 16, 64));
    m = fmaxf(m, __shfl_xor(m, 32, 64));
    return m;
}

// Barrier-free per-wave conv: NT tiles {tbase..tbase+NT-1}, words [w0, w0+WCNT).
// Wave-private LDS double-buffer; 1-deep pipeline on ids + charP rows.
template <int NT, int WCNT>
__device__ __forceinline__ void conv_wave(int tbase, int w0, int lane,
                                          ushort* __restrict__ sl,
                                          const int* __restrict__ chars,
                                          const ushort* __restrict__ charP,
                                          const ushort* __restrict__ WO,
                                          const float* __restrict__ conv_b,
                                          float* __restrict__ out) {
    const int l15 = lane & 15;
    const int lg  = lane >> 4;
    const int blk = lane & 7;
    const int l_0 = lane >> 3;           // rows 0..7   (task = lane)
    const int l_1 = (64 + lane) >> 3;    // rows 8..15  (task = 64+lane)
    const int l_2 = (128 + lane) >> 3;   // rows 16..17 (lane<16 only)

    // swizzled LDS write offsets (same swizzle as the proven r4 kernel)
    const int wo0 = l_0 * 64 + ((blk ^ (l_0 & 7)) << 3);
    const int wo1 = l_1 * 64 + ((blk ^ (l_1 & 7)) << 3);

    // zero rows 16/17 of both buffers once (conv padding rows)
    if (lane < 16) {
        const int wo2 = l_2 * 64 + ((blk ^ (l_2 & 7)) << 3);
        short8 z = {};
        *(short8*)&sl[wo2] = z;
        *(short8*)&sl[SLICE + wo2] = z;
    }

    // B fragments + bias (held in regs for the whole strip)
    short8 B[NT][6];
    float  bv[NT];
    #pragma unroll
    for (int i = 0; i < NT; i++) {
        int col = (tbase + i) * 16 + l15;
        #pragma unroll
        for (int s = 0; s < 6; s++)
            B[i][s] = *(const short8*)&WO[col * KPAD + s * 32 + lg * 8];
        bv[i] = (col < OUT_CH) ? conv_b[col] : 0.f;
    }

    // prologue: word 0 ids + charP rows
    int iv = 0;
    {
        int m0 = w0;
        if (lane < 16) iv = chars[((m0 & 63) * SENT + (m0 >> 6)) * WLEN + l15];
    }
    short8 gA, gB;
    {
        int id0 = __shfl(iv, l_0, 64);
        int id1 = __shfl(iv, l_1, 64);
        gA = *(const short8*)&charP[id0 * 64 + blk * 8];
        gB = *(const short8*)&charP[id1 * 64 + blk * 8];
    }

    #pragma unroll 1
    for (int r = 0; r < WCNT; r++) {
        const int m = w0 + r;
        ushort* __restrict__ buf = sl + (r & 1) * SLICE;

        // prefetch next word's ids (global, issued early)
        int iv_nxt = 0;
        {
            int rn = (r + 1 < WCNT) ? (r + 1) : r;
            int mn = w0 + rn;
            if (lane < 16) iv_nxt = chars[((mn & 63) * SENT + (mn >> 6)) * WLEN + l15];
        }

        // stage current word into wave-private buffer
        *(short8*)&buf[wo0] = gA;
        *(short8*)&buf[wo1] = gB;
        __builtin_amdgcn_wave_barrier();
        asm volatile("s_waitcnt lgkmcnt(0)" ::: "memory");
        __builtin_amdgcn_wave_barrier();

        // A fragments
        short8 a[6];
        #pragma unroll
        for (int s = 0; s < 6; s++) {
            int l  = l15 + (s >> 1);
            int bb = (((s & 1) * 4 + lg) ^ (l & 7));
            a[s] = *(const short8*)&buf[l * 64 + (bb << 3)];
        }

        float4v acc[NT];
        #pragma unroll
        for (int i = 0; i < NT; i++) acc[i] = (float4v){0, 0, 0, 0};
        #pragma unroll
        for (int s = 0; s < 6; s++)
            #pragma unroll
            for (int i = 0; i < NT; i++)
                acc[i] = __builtin_amdgcn_mfma_f32_16x16x32_bf16(a[s], B[i][s], acc[i], 0, 0, 0);

        // prefetch next word's charP rows (hides L1/L2 latency under reduce/store)
        {
            int id0 = __shfl(iv_nxt, l_0, 64);
            int id1 = __shfl(iv_nxt, l_1, 64);
            gA = *(const short8*)&charP[id0 * 64 + blk * 8];
            gB = *(const short8*)&charP[id1 * 64 + blk * 8];
        }

        // reduce + bias + store
        float* obase = out + (size_t)m * D_OUT + D_WORDE;
        #pragma unroll
        for (int i = 0; i < NT; i++) {
            float mx = redmax14(acc[i], lg) + bv[i];
            int col = (tbase + i) * 16 + lane;
            if (lane < 16 && col < OUT_CH) obase[col] = mx;
        }
    }
}

// ---------- fused: even blocks = conv (barrier-free waves), odd = emb copy ----------
__global__ void __launch_bounds__(256)
fused_kernel(const int* __restrict__ words, const int* __restrict__ chars,
             const float* __restrict__ W_word, const ushort* __restrict__ ws,
             const float* __restrict__ conv_b, float* __restrict__ out) {
    __shared__ __align__(16) ushort smem[4 * 2 * SLICE];

    const int wave = threadIdx.x >> 6;
    const int lane = threadIdx.x & 63;

    if (blockIdx.x & 1) {
        // ---- word embedding: one wave per output row, float4 copy
        const int m   = (blockIdx.x >> 1) * 4 + wave;      // 0..16383
        const int idx = words[m];
        const float4v* __restrict__ src = (const float4v*)(W_word + (size_t)idx * D_WORDE);
        float4v* __restrict__ dst = (float4v*)(out + (size_t)m * D_OUT);
        dst[lane] = src[lane];                             // 75 float4 per row
        if (lane < 75 - 64) dst[64 + lane] = src[64 + lane];
        return;
    }

    const int cb = blockIdx.x >> 1;
    if (cb >= CONV_BLOCKS) return;

    const ushort* __restrict__ charP = ws;
    const ushort* __restrict__ WO    = ws + CHARP_U16;
    ushort* sl = smem + wave * (2 * SLICE);

    const int u = cb * 4 + wave;
    if (u < NCLS * CLASS_WAVES) {
        const int cls   = u >> 11;                         // /2048
        const int strip = (u & (CLASS_WAVES - 1)) * WPW;
        conv_wave<2, WPW>(cls * 2, strip, lane, sl, chars, charP, WO, conv_b, out);
    } else {
        const int strip = (u - NCLS * CLASS_WAVES) * T12_WPW;
        conv_wave<1, T12_WPW>(12, strip, lane, sl, chars, charP, WO, conv_b, out);
    }
}

// ---------- fallbacks (tiny ws): round-1 proven kernels ----------
__global__ void __launch_bounds__(256)
word_emb_kernel(const int* __restrict__ words, const float* __restrict__ W_word,
                float* __restrict__ out) {
    int wave = threadIdx.x >> 6, lane = threadIdx.x & 63;
    int m = blockIdx.x * 4 + wave;
    int idx = words[m];
    const float* __restrict__ src = W_word + (size_t)idx * D_WORDE;
    float* __restrict__ dst = out + (size_t)m * D_OUT;
    for (int j = lane; j < D_WORDE; j += 64) dst[j] = src[j];
}

__global__ void __launch_bounds__(256)
char_conv_f32_kernel(const int* __restrict__ chars, const float* __restrict__ W_char,
                     const float* __restrict__ conv_w, const float* __restrict__ conv_b,
                     float* __restrict__ out) {
    __shared__ __align__(16) float xs[D_CHARE * WLEN];
    __shared__ int ids[WLEN];
    int m = blockIdx.x, s = m >> 6, b = m & 63, tid = threadIdx.x;
    if (tid < WLEN) ids[tid] = chars[(b * SENT + s) * WLEN + tid];
    __syncthreads();
    for (int e = tid; e < D_CHARE * WLEN; e += 256) {
        int c = e >> 4, l = e & 15;
        xs[e] = W_char[ids[l] * D_CHARE + c];
    }
    __syncthreads();
    if (tid < OUT_CH) {
        float acc[NPOS];
        #pragma unroll
        for (int p = 0; p < NPOS; p++) acc[p] = 0.f;
        const float4* xs4 = (const float4*)xs;
        for (int c = 0; c < D_CHARE; c++) {
            float4 a0 = xs4[c*4+0], a1 = xs4[c*4+1], a2 = xs4[c*4+2], a3 = xs4[c*4+3];
            float xr[WLEN] = {a0.x,a0.y,a0.z,a0.w, a1.x,a1.y,a1.z,a1.w,
                              a2.x,a2.y,a2.z,a2.w, a3.x,a3.y,a3.z,a3.w};
            #pragma unroll
            for (int k = 0; k < KSIZE; k++) {
                float wv = conv_w[tid * (D_CHARE * KSIZE) + c * KSIZE + k];
                #pragma unroll
                for (int p = 0; p < NPOS; p++) acc[p] = fmaf(wv, xr[p + k], acc[p]);
            }
        }
        float mx = acc[0];
        #pragma unroll
        for (int p = 1; p < NPOS; p++) mx = fmaxf(mx, acc[p]);
        out[(size_t)m * D_OUT + D_WORDE + tid] = mx + conv_b[tid];
    }
}

extern "C" void kernel_launch(void* const* d_in, const int* in_sizes, int n_in,
                              void* d_out, int out_size, void* d_ws, size_t ws_size,
                              hipStream_t stream) {
    const int*   words  = (const int*)d_in[0];
    const int*   chars  = (const int*)d_in[1];
    const float* W_word = (const float*)d_in[2];
    const float* W_char = (const float*)d_in[3];
    const float* conv_w = (const float*)d_in[4];
    const float* conv_b = (const float*)d_in[5];
    float* out = (float*)d_out;

    if (ws_size >= WS_NEED) {
        ushort* ws = (ushort*)d_ws;
        hipLaunchKernelGGL(prep_kernel,
                           dim3((CHARP_U16 + WO_U16 + 255) / 256), dim3(256), 0, stream,
                           W_char, conv_w, ws);
        hipLaunchKernelGGL(fused_kernel, dim3(GRID), dim3(256), 0, stream,
                           words, chars, W_word, ws, conv_b, out);
    } else {
        hipLaunchKernelGGL(word_emb_kernel, dim3(NWORDS / 4), dim3(256), 0, stream,
                           words, W_word, out);
        hipLaunchKernelGGL(char_conv_f32_kernel, dim3(NWORDS), dim3(256), 0, stream,
                           chars, W_char, conv_w, conv_b, out);
    }
}

// Round 8
// 64.407 us; speedup vs baseline: 2.1064x; 1.4232x over previous
//
#include <hip/hip_runtime.h>

#define SENT    256
#define BATCH   64
#define WLEN    16
#define D_WORDE 300
#define D_CHARE 50
#define OUT_CH  200
#define KSIZE   3
#define NPOS    14
#define D_OUT   500
#define NWORDS  (SENT * BATCH)

// GEMM geometry: M=16 positions/word, N=13x16=208, K=3*64=192 (kg=kk*64+c)
#define KPAD      192
#define MPAD      208
#define CHARP_U16 (129 * 64)          // row 128 = zeros (conv rows 16/17 + branchless staging)
#define WO_U16    (MPAD * KPAD)
#define WS_NEED   ((size_t)(CHARP_U16 + WO_U16) * 2)

#define WPB         8                 // words per block
#define TILE_U16    1160              // 18*64 + 8 pad (per-word LDS tile, ushorts)
#define CONV_BLOCKS (NWORDS / WPB)    // 2048

typedef short  short8  __attribute__((ext_vector_type(8)));
typedef ushort ushort8 __attribute__((ext_vector_type(8)));
typedef float  float4v __attribute__((ext_vector_type(4)));

__device__ __forceinline__ ushort f2bf(float f) {
    unsigned u = __float_as_uint(f);
    u = (u + 0x7FFFu + ((u >> 16) & 1u)) >> 16;   // RNE
    return (ushort)u;
}

// ---------- prep: bf16 char table (129 rows) + K-major conv weights ----------
__global__ void prep_kernel(const float* __restrict__ W_char,
                            const float* __restrict__ conv_w,
                            ushort* __restrict__ ws) {
    int j = blockIdx.x * 256 + threadIdx.x;
    if (j < CHARP_U16) {
        int r = j >> 6, c = j & 63;
        ws[j] = (r < 128 && c < D_CHARE) ? f2bf(W_char[r * D_CHARE + c]) : (ushort)0;
    }
    int j2 = j - CHARP_U16;
    if (j2 >= 0 && j2 < WO_U16) {
        int o = j2 / KPAD, kg = j2 - o * KPAD;
        int kk = kg >> 6, c = kg & 63;
        float v = (o < OUT_CH && c < D_CHARE)
                    ? conv_w[o * (D_CHARE * KSIZE) + c * KSIZE + kk] : 0.f;
        ws[CHARP_U16 + j2] = f2bf(v);
    }
}

__device__ __forceinline__ float redmax14(float4v d, int lg) {
    float m01 = fmaxf(d[0], d[1]);
    float m23 = fmaxf(d[2], d[3]);
    float m = (lg == 3) ? m01 : fmaxf(m01, m23);   // rows 14,15 invalid
    m = fmaxf(m, __shfl_xor(m, 16, 64));
    m = fmaxf(m, __shfl_xor(m, 32, 64));
    return m;
}

// ---------- fused uniform block: conv (MFMA, A-pipelined) + emb copy tail ----------
// NO __launch_bounds__ min-waves: every forced-occupancy attempt spilled
// (r5: cap64 -> VGPR 32 + 336MB scratch; r6: cap85 -> VGPR 40 + 175MB).
__global__ void __launch_bounds__(256)
fused_kernel(const int* __restrict__ words, const int* __restrict__ chars,
             const float* __restrict__ W_word, const ushort* __restrict__ ws,
             const float* __restrict__ conv_b, float* __restrict__ out) {
    __shared__ __align__(16) ushort smem[WPB * TILE_U16];

    const int tid  = threadIdx.x;
    const int lane = tid & 63;
    const int wave = tid >> 6;

    const ushort* __restrict__ charP = ws;
    const ushort* __restrict__ WO    = ws + CHARP_U16;
    const int block0 = blockIdx.x * WPB;
    const int l15 = lane & 15;
    const int lg  = lane >> 4;

    // ---- B fragments + bias issued FIRST (global latency hides under staging)
    short8 B[3][6];
    float  bv[3];
    #pragma unroll
    for (int i = 0; i < 3; i++) {
        int col = (wave + 4 * i) * 16 + l15;                  // <= 191, all valid
        #pragma unroll
        for (int s = 0; s < 6; s++)
            B[i][s] = *(const short8*)&WO[col * KPAD + s * 32 + lg * 8];
        bv[i] = conv_b[col];
    }

    // ---- stage 8 word-tiles directly (no ids[] round-trip, branchless via zero row 128)
    {
        int task = tid;
        #pragma unroll
        for (int t = 0; t < 5; t++) {
            if (t < 4 || task < WPB * 144) {
                int word = task / 144;
                int rem  = task - word * 144;
                int l = rem >> 3, blk = rem & 7;
                int m = block0 + word;
                int id = (l < WLEN) ? chars[((m & 63) * SENT + (m >> 6)) * WLEN + l] : 128;
                ushort8 v = *(const ushort8*)&charP[id * 64 + blk * 8];
                *(ushort8*)&smem[word * TILE_U16 + l * 64 + ((blk ^ (l & 7)) << 3)] = v;
            }
            task += 256;
        }
    }
    __syncthreads();

    // ---- phase 1: wave w owns N-tiles {w, w+4, w+8}; 1-deep A pipeline over 8 words
#define LOAD_A(dst, widx)                                                    \
    {                                                                        \
        const int base_ = (widx) * TILE_U16;                                 \
        _Pragma("unroll")                                                    \
        for (int s = 0; s < 6; s++) {                                        \
            int l_  = l15 + (s >> 1);                                        \
            int bb_ = (((s & 1) * 4 + lg) ^ (l_ & 7));                       \
            dst[s] = *(const short8*)&smem[base_ + l_ * 64 + (bb_ << 3)];    \
        }                                                                    \
    }

#define MFMA_RED_STORE(a_, widx)                                             \
    {                                                                        \
        float4v acc_[3];                                                     \
        _Pragma("unroll")                                                    \
        for (int i = 0; i < 3; i++) acc_[i] = (float4v){0, 0, 0, 0};         \
        _Pragma("unroll")                                                    \
        for (int s = 0; s < 6; s++)                                          \
            _Pragma("unroll")                                                \
            for (int i = 0; i < 3; i++)                                      \
                acc_[i] = __builtin_amdgcn_mfma_f32_16x16x32_bf16(           \
                    a_[s], B[i][s], acc_[i], 0, 0, 0);                       \
        float* obase_ = out + (size_t)(block0 + (widx)) * D_OUT + D_WORDE;   \
        _Pragma("unroll")                                                    \
        for (int i = 0; i < 3; i++) {                                        \
            float mx_ = redmax14(acc_[i], lg) + bv[i];                       \
            if (lane < 16) obase_[(wave + 4 * i) * 16 + lane] = mx_;         \
        }                                                                    \
    }

    {
        short8 aA[6], aB[6];
        LOAD_A(aA, 0)
        #pragma unroll 1
        for (int r = 0; r < WPB; r += 2) {
            LOAD_A(aB, r + 1)
            MFMA_RED_STORE(aA, r)
            if (r + 2 < WPB) LOAD_A(aA, r + 2)
            MFMA_RED_STORE(aB, r + 1)
        }
    }

    // ---- phase 2: tile 12 (channels 192..199); wave w does words {2w, 2w+1}
    {
        short8 B12[6];
        #pragma unroll
        for (int s = 0; s < 6; s++)
            B12[s] = *(const short8*)&WO[(192 + l15) * KPAD + s * 32 + lg * 8];
        const float bv12 = (l15 < 8) ? conv_b[192 + l15] : 0.f;

        #pragma unroll 1
        for (int r2 = 0; r2 < 2; r2++) {
            const int widx = 2 * wave + r2;
            short8 a[6];
            LOAD_A(a, widx)
            float4v acc = {0, 0, 0, 0};
            #pragma unroll
            for (int s = 0; s < 6; s++)
                acc = __builtin_amdgcn_mfma_f32_16x16x32_bf16(a[s], B12[s], acc, 0, 0, 0);
            float mx = redmax14(acc, lg) + bv12;
            if (lane < 8)
                out[(size_t)(block0 + widx) * D_OUT + D_WORDE + 192 + lane] = mx;
        }
    }

    // ---- memory tail: word-emb copy for this block's 8 words (2 rows/wave)
    #pragma unroll
    for (int r = 0; r < 2; r++) {
        const int m   = block0 + wave * 2 + r;
        const int idx = words[m];
        const float4v* __restrict__ src = (const float4v*)(W_word + (size_t)idx * D_WORDE);
        float4v* __restrict__ dst = (float4v*)(out + (size_t)m * D_OUT);
        dst[lane] = src[lane];                                 // 75 float4 per row
        if (lane < 75 - 64) dst[64 + lane] = src[64 + lane];
    }
#undef LOAD_A
#undef MFMA_RED_STORE
}

// ---------- fallbacks (tiny ws): round-1 proven kernels ----------
__global__ void __launch_bounds__(256)
word_emb_kernel(const int* __restrict__ words, const float* __restrict__ W_word,
                float* __restrict__ out) {
    int wave = threadIdx.x >> 6, lane = threadIdx.x & 63;
    int m = blockIdx.x * 4 + wave;
    int idx = words[m];
    const float* __restrict__ src = W_word + (size_t)idx * D_WORDE;
    float* __restrict__ dst = out + (size_t)m * D_OUT;
    for (int j = lane; j < D_WORDE; j += 64) dst[j] = src[j];
}

__global__ void __launch_bounds__(256)
char_conv_f32_kernel(const int* __restrict__ chars, const float* __restrict__ W_char,
                     const float* __restrict__ conv_w, const float* __restrict__ conv_b,
                     float* __restrict__ out) {
    __shared__ __align__(16) float xs[D_CHARE * WLEN];
    __shared__ int ids[WLEN];
    int m = blockIdx.x, s = m >> 6, b = m & 63, tid = threadIdx.x;
    if (tid < WLEN) ids[tid] = chars[(b * SENT + s) * WLEN + tid];
    __syncthreads();
    for (int e = tid; e < D_CHARE * WLEN; e += 256) {
        int c = e >> 4, l = e & 15;
        xs[e] = W_char[ids[l] * D_CHARE + c];
    }
    __syncthreads();
    if (tid < OUT_CH) {
        float acc[NPOS];
        #pragma unroll
        for (int p = 0; p < NPOS; p++) acc[p] = 0.f;
        const float4* xs4 = (const float4*)xs;
        for (int c = 0; c < D_CHARE; c++) {
            float4 a0 = xs4[c*4+0], a1 = xs4[c*4+1], a2 = xs4[c*4+2], a3 = xs4[c*4+3];
            float xr[WLEN] = {a0.x,a0.y,a0.z,a0.w, a1.x,a1.y,a1.z,a1.w,
                              a2.x,a2.y,a2.z,a2.w, a3.x,a3.y,a3.z,a3.w};
            #pragma unroll
            for (int k = 0; k < KSIZE; k++) {
                float wv = conv_w[tid * (D_CHARE * KSIZE) + c * KSIZE + k];
                #pragma unroll
                for (int p = 0; p < NPOS; p++) acc[p] = fmaf(wv, xr[p + k], acc[p]);
            }
        }
        float mx = acc[0];
        #pragma unroll
        for (int p = 1; p < NPOS; p++) mx = fmaxf(mx, acc[p]);
        out[(size_t)m * D_OUT + D_WORDE + tid] = mx + conv_b[tid];
    }
}

extern "C" void kernel_launch(void* const* d_in, const int* in_sizes, int n_in,
                              void* d_out, int out_size, void* d_ws, size_t ws_size,
                              hipStream_t stream) {
    const int*   words  = (const int*)d_in[0];
    const int*   chars  = (const int*)d_in[1];
    const float* W_word = (const float*)d_in[2];
    const float* W_char = (const float*)d_in[3];
    const float* conv_w = (const float*)d_in[4];
    const float* conv_b = (const float*)d_in[5];
    float* out = (float*)d_out;

    if (ws_size >= WS_NEED) {
        ushort* ws = (ushort*)d_ws;
        hipLaunchKernelGGL(prep_kernel,
                           dim3((CHARP_U16 + WO_U16 + 255) / 256), dim3(256), 0, stream,
                           W_char, conv_w, ws);
        hipLaunchKernelGGL(fused_kernel, dim3(CONV_BLOCKS), dim3(256), 0, stream,
                           words, chars, W_word, ws, conv_b, out);
    } else {
        hipLaunchKernelGGL(word_emb_kernel, dim3(NWORDS / 4), dim3(256), 0, stream,
                           words, W_word, out);
        hipLaunchKernelGGL(char_conv_f32_kernel, dim3(NWORDS), dim3(256), 0, stream,
                           chars, W_char, conv_w, conv_b, out);
    }
}

// Round 9
// 54.025 us; speedup vs baseline: 2.5112x; 1.1922x over previous
//
#include <hip/hip_runtime.h>

#define SENT    256
#define BATCH   64
#define WLEN    16
#define D_WORDE 300
#define D_CHARE 50
#define OUT_CH  200
#define KSIZE   3
#define NPOS    14
#define D_OUT   500
#define NWORDS  (SENT * BATCH)

// GEMM geometry: M=16 positions/word, N=13x16=208, K=3*64=192 (kg=kk*64+c)
#define KPAD      192
#define MPAD      208
#define CHARP_U16 (129 * 64)          // row 128 legacy-zero (unused by flat layout)
#define WO_U16    (MPAD * KPAD)
#define WS_NEED   ((size_t)(CHARP_U16 + WO_U16) * 2)

#define WPB         8                 // words per conv block
#define TILE_ROWS   (WPB * 16 + 2)    // flat 16 rows/word + 2 trailing slack rows
#define CONV_BLOCKS (NWORDS / WPB)    // 2048
#define EMB_BLOCKS  (NWORDS / 4)      // 4096
#define GRID        (CONV_BLOCKS + EMB_BLOCKS)   // 6144; conv when blockIdx%3==0

typedef short  short8  __attribute__((ext_vector_type(8)));
typedef ushort ushort8 __attribute__((ext_vector_type(8)));
typedef float  float4v __attribute__((ext_vector_type(4)));

__device__ __forceinline__ ushort f2bf(float f) {
    unsigned u = __float_as_uint(f);
    u = (u + 0x7FFFu + ((u >> 16) & 1u)) >> 16;   // RNE
    return (ushort)u;
}

// ---------- prep: bf16 char table (129 rows) + K-major conv weights ----------
__global__ void prep_kernel(const float* __restrict__ W_char,
                            const float* __restrict__ conv_w,
                            ushort* __restrict__ ws) {
    int j = blockIdx.x * 256 + threadIdx.x;
    if (j < CHARP_U16) {
        int r = j >> 6, c = j & 63;
        ws[j] = (r < 128 && c < D_CHARE) ? f2bf(W_char[r * D_CHARE + c]) : (ushort)0;
    }
    int j2 = j - CHARP_U16;
    if (j2 >= 0 && j2 < WO_U16) {
        int o = j2 / KPAD, kg = j2 - o * KPAD;
        int kk = kg >> 6, c = kg & 63;
        float v = (o < OUT_CH && c < D_CHARE)
                    ? conv_w[o * (D_CHARE * KSIZE) + c * KSIZE + kk] : 0.f;
        ws[CHARP_U16 + j2] = f2bf(v);
    }
}

__device__ __forceinline__ float redmax14(float4v d, int lg) {
    float m01 = fmaxf(d[0], d[1]);
    float m23 = fmaxf(d[2], d[3]);
    float m = (lg == 3) ? m01 : fmaxf(m01, m23);   // rows 14,15 excluded (garbage-safe)
    m = fmaxf(m, __shfl_xor(m, 16, 64));
    m = fmaxf(m, __shfl_xor(m, 32, 64));
    return m;
}

// ---------- fused grid: conv blocks (%3==0) + emb-copy blocks ----------
// NO __launch_bounds__ min-waves (r5/r6/r8: every forced-occupancy or
// register-pipeline attempt spilled or crossed the 64-VGPR wave cliff).
__global__ void __launch_bounds__(256)
fused_kernel(const int* __restrict__ words, const int* __restrict__ chars,
             const float* __restrict__ W_word, const ushort* __restrict__ ws,
             const float* __restrict__ conv_b, float* __restrict__ out) {
    __shared__ __align__(16) ushort tile[TILE_ROWS * 64];   // 16640 B

    const int tid  = threadIdx.x;
    const int lane = tid & 63;
    const int wave = tid >> 6;

    if (blockIdx.x % 3 != 0) {
        // ---- word embedding: one wave per output row, float4 copy
        const int eb = blockIdx.x - blockIdx.x / 3 - 1;       // 0..4095
        const int m  = eb * 4 + wave;
        const int idx = words[m];
        const float4v* __restrict__ src = (const float4v*)(W_word + (size_t)idx * D_WORDE);
        float4v* __restrict__ dst = (float4v*)(out + (size_t)m * D_OUT);
        dst[lane] = src[lane];                                 // 75 float4 per row
        if (lane < 75 - 64) dst[64 + lane] = src[64 + lane];
        return;
    }

    const ushort* __restrict__ charP = ws;
    const ushort* __restrict__ WO    = ws + CHARP_U16;
    const int block0 = (blockIdx.x / 3) * WPB;
    const int l15 = lane & 15;
    const int lg  = lane >> 4;

    // ---- B fragments + bias first (latency hides under staging)
    short8 B[3][6];
    float  bv[3];
    #pragma unroll
    for (int i = 0; i < 3; i++) {
        int col = (wave + 4 * i) * 16 + l15;                  // <= 191, all valid
        #pragma unroll
        for (int s = 0; s < 6; s++)
            B[i][s] = *(const short8*)&WO[col * KPAD + s * 32 + lg * 8];
        bv[i] = conv_b[col];
    }

    // ---- stage: flat [WPB*16 rows][64 cols], pow2 addressing, no pad/zero rows
    #pragma unroll
    for (int t = 0; t < 4; t++) {
        int task = tid + t * 256;                 // 0..1023
        int word = task >> 7;
        int l    = (task >> 3) & 15;
        int blk  = task & 7;
        int m    = block0 + word;
        int id   = chars[((m & 63) * SENT + (m >> 6)) * WLEN + l];
        ushort8 v = *(const ushort8*)&charP[id * 64 + blk * 8];
        tile[((word << 4) | l) * 64 + ((blk ^ (l & 7)) << 3)] = v[0];  // placeholder; replaced below
        *(ushort8*)&tile[((word << 4) | l) * 64 + ((blk ^ (l & 7)) << 3)] = v;
    }
    __syncthreads();

    // ---- loop-invariant swizzled LDS offsets (ushort units); word stride = 1024
    int offA[6];
    #pragma unroll
    for (int s = 0; s < 6; s++) {
        int l  = l15 + (s >> 1);                  // 0..17 (overflow rows are slack)
        int bb = (((s & 1) * 4 + lg) ^ (l & 7));
        offA[s] = l * 64 + (bb << 3);
    }

    // ---- phase 1: wave w owns N-tiles {w, w+4, w+8}; serial per word (VGPR-lean)
    #pragma unroll 1
    for (int r = 0; r < WPB; r++) {
        const int base = r << 10;                 // r*1024 ushorts
        short8 a[6];
        #pragma unroll
        for (int s = 0; s < 6; s++)
            a[s] = *(const short8*)&tile[base + offA[s]];
        float4v acc[3];
        #pragma unroll
        for (int i = 0; i < 3; i++) acc[i] = (float4v){0, 0, 0, 0};
        #pragma unroll
        for (int s = 0; s < 6; s++)
            #pragma unroll
            for (int i = 0; i < 3; i++)
                acc[i] = __builtin_amdgcn_mfma_f32_16x16x32_bf16(a[s], B[i][s], acc[i], 0, 0, 0);

        float* obase = out + (size_t)(block0 + r) * D_OUT + D_WORDE;
        #pragma unroll
        for (int i = 0; i < 3; i++) {
            float mx = redmax14(acc[i], lg) + bv[i];
            if (lane < 16) obase[(wave + 4 * i) * 16 + lane] = mx;
        }
    }

    // ---- phase 2: tile 12 (channels 192..199); wave w does words {2w, 2w+1}
    {
        short8 B12[6];
        #pragma unroll
        for (int s = 0; s < 6; s++)
            B12[s] = *(const short8*)&WO[(192 + l15) * KPAD + s * 32 + lg * 8];
        const float bv12 = (l15 < 8) ? conv_b[192 + l15] : 0.f;

        #pragma unroll 1
        for (int r2 = 0; r2 < 2; r2++) {
            const int widx = 2 * wave + r2;
            const int base = widx << 10;
            short8 a[6];
            #pragma unroll
            for (int s = 0; s < 6; s++)
                a[s] = *(const short8*)&tile[base + offA[s]];
            float4v acc = {0, 0, 0, 0};
            #pragma unroll
            for (int s = 0; s < 6; s++)
                acc = __builtin_amdgcn_mfma_f32_16x16x32_bf16(a[s], B12[s], acc, 0, 0, 0);
            float mx = redmax14(acc, lg) + bv12;
            if (lane < 8)
                out[(size_t)(block0 + widx) * D_OUT + D_WORDE + 192 + lane] = mx;
        }
    }
}

// ---------- fallbacks (tiny ws): round-1 proven kernels ----------
__global__ void __launch_bounds__(256)
word_emb_kernel(const int* __restrict__ words, const float* __restrict__ W_word,
                float* __restrict__ out) {
    int wave = threadIdx.x >> 6, lane = threadIdx.x & 63;
    int m = blockIdx.x * 4 + wave;
    int idx = words[m];
    const float* __restrict__ src = W_word + (size_t)idx * D_WORDE;
    float* __restrict__ dst = out + (size_t)m * D_OUT;
    for (int j = lane; j < D_WORDE; j += 64) dst[j] = src[j];
}

__global__ void __launch_bounds__(256)
char_conv_f32_kernel(const int* __restrict__ chars, const float* __restrict__ W_char,
                     const float* __restrict__ conv_w, const float* __restrict__ conv_b,
                     float* __restrict__ out) {
    __shared__ __align__(16) float xs[D_CHARE * WLEN];
    __shared__ int ids[WLEN];
    int m = blockIdx.x, s = m >> 6, b = m & 63, tid = threadIdx.x;
    if (tid < WLEN) ids[tid] = chars[(b * SENT + s) * WLEN + tid];
    __syncthreads();
    for (int e = tid; e < D_CHARE * WLEN; e += 256) {
        int c = e >> 4, l = e & 15;
        xs[e] = W_char[ids[l] * D_CHARE + c];
    }
    __syncthreads();
    if (tid < OUT_CH) {
        float acc[NPOS];
        #pragma unroll
        for (int p = 0; p < NPOS; p++) acc[p] = 0.f;
        const float4* xs4 = (const float4*)xs;
        for (int c = 0; c < D_CHARE; c++) {
            float4 a0 = xs4[c*4+0], a1 = xs4[c*4+1], a2 = xs4[c*4+2], a3 = xs4[c*4+3];
            float xr[WLEN] = {a0.x,a0.y,a0.z,a0.w, a1.x,a1.y,a1.z,a1.w,
                              a2.x,a2.y,a2.z,a2.w, a3.x,a3.y,a3.z,a3.w};
            #pragma unroll
            for (int k = 0; k < KSIZE; k++) {
                float wv = conv_w[tid * (D_CHARE * KSIZE) + c * KSIZE + k];
                #pragma unroll
                for (int p = 0; p < NPOS; p++) acc[p] = fmaf(wv, xr[p + k], acc[p]);
            }
        }
        float mx = acc[0];
        #pragma unroll
        for (int p = 1; p < NPOS; p++) mx = fmaxf(mx, acc[p]);
        out[(size_t)m * D_OUT + D_WORDE + tid] = mx + conv_b[tid];
    }
}

extern "C" void kernel_launch(void* const* d_in, const int* in_sizes, int n_in,
                              void* d_out, int out_size, void* d_ws, size_t ws_size,
                              hipStream_t stream) {
    const int*   words  = (const int*)d_in[0];
    const int*   chars  = (const int*)d_in[1];
    const float* W_word = (const float*)d_in[2];
    const float* W_char = (const float*)d_in[3];
    const float* conv_w = (const float*)d_in[4];
    const float* conv_b = (const float*)d_in[5];
    float* out = (float*)d_out;

    if (ws_size >= WS_NEED) {
        ushort* ws = (ushort*)d_ws;
        hipLaunchKernelGGL(prep_kernel,
                           dim3((CHARP_U16 + WO_U16 + 255) / 256), dim3(256), 0, stream,
                           W_char, conv_w, ws);
        hipLaunchKernelGGL(fused_kernel, dim3(GRID), dim3(256), 0, stream,
                           words, chars, W_word, ws, conv_b, out);
    } else {
        hipLaunchKernelGGL(word_emb_kernel, dim3(NWORDS / 4), dim3(256), 0, stream,
                           words, W_word, out);
        hipLaunchKernelGGL(char_conv_f32_kernel, dim3(NWORDS), dim3(256), 0, stream,
                           chars, W_char, conv_w, conv_b, out);
    }
}